// Round 1
// baseline (544.825 us; speedup 1.0000x reference)
//
#include <hip/hip_runtime.h>

#define H 768
#define FF 3072
#define NH 12
#define DH 64
#define SEQ 2048
#define MTOK 4096

typedef __attribute__((ext_vector_type(8))) short short8;
typedef __attribute__((ext_vector_type(4))) float f32x4;

__device__ __forceinline__ f32x4 mfma16(short8 a, short8 b, f32x4 c) {
  return __builtin_amdgcn_mfma_f32_16x16x32_bf16(a, b, c, 0, 0, 0);
}

__device__ __forceinline__ unsigned short f2bf(float f) {
  union { float f; unsigned int u; } c; c.f = f;
  unsigned int u = c.u;
  u += 0x7fffu + ((u >> 16) & 1u);  // round-to-nearest-even
  return (unsigned short)(u >> 16);
}
__device__ __forceinline__ float bf2f(unsigned short s) {
  union { unsigned int u; float f; } c; c.u = ((unsigned int)s) << 16;
  return c.f;
}

// ---------------- transpose + cast: in fp32 [K][N] -> out bf16 [N][K] ----------------
__global__ __launch_bounds__(256) void transpose_cast(const float* __restrict__ in,
                                                      unsigned short* __restrict__ out,
                                                      int K, int N) {
  __shared__ float tile[32][33];
  int nb = N >> 5;
  int n0 = (blockIdx.x % nb) << 5;
  int k0 = (blockIdx.x / nb) << 5;
  int tx = threadIdx.x & 31, ty = threadIdx.x >> 5;  // ty 0..7
#pragma unroll
  for (int yy = 0; yy < 4; ++yy)
    tile[ty + yy * 8][tx] = in[(size_t)(k0 + ty + yy * 8) * N + n0 + tx];
  __syncthreads();
#pragma unroll
  for (int yy = 0; yy < 4; ++yy)
    out[(size_t)(n0 + ty + yy * 8) * K + k0 + tx] = f2bf(tile[tx][ty + yy * 8]);
}

// ---------------- LayerNorm fp32 [rows][768] -> bf16 ----------------
__global__ __launch_bounds__(256) void ln_kernel(const float* __restrict__ x,
                                                 const float* __restrict__ w,
                                                 const float* __restrict__ b,
                                                 unsigned short* __restrict__ out) {
  int row = blockIdx.x;
  int tid = threadIdx.x;
  const float* xr = x + (size_t)row * H;
  float v0 = xr[tid], v1 = xr[tid + 256], v2 = xr[tid + 512];
  float s = v0 + v1 + v2;
  float ss = v0 * v0 + v1 * v1 + v2 * v2;
#pragma unroll
  for (int off = 32; off > 0; off >>= 1) {
    s += __shfl_down(s, off);
    ss += __shfl_down(ss, off);
  }
  __shared__ float red[8];
  int wave = tid >> 6, lane = tid & 63;
  if (lane == 0) { red[wave] = s; red[4 + wave] = ss; }
  __syncthreads();
  s = red[0] + red[1] + red[2] + red[3];
  ss = red[4] + red[5] + red[6] + red[7];
  float mu = s * (1.0f / H);
  float var = ss * (1.0f / H) - mu * mu;
  float rs = rsqrtf(var + 1e-6f);
  unsigned short* orow = out + (size_t)row * H;
  orow[tid]       = f2bf((v0 - mu) * rs * w[tid]       + b[tid]);
  orow[tid + 256] = f2bf((v1 - mu) * rs * w[tid + 256] + b[tid + 256]);
  orow[tid + 512] = f2bf((v2 - mu) * rs * w[tid + 512] + b[tid + 512]);
}

// ---------------- GEMM: C[M,N] = A[M,K](bf16) @ Bt[N,K]^T(bf16), fused epilogues ----------------
enum { MODE_QKV = 0, MODE_RESID = 1, MODE_GELU = 2 };

template <int MODE>
__global__ __launch_bounds__(256) void gemm_kernel(
    const unsigned short* __restrict__ A,   // [M,K] bf16
    const unsigned short* __restrict__ Bt,  // [N,K] bf16
    int M, int N, int K,
    const float* __restrict__ bias0,
    const float* __restrict__ bias1,
    const float* __restrict__ bias2,
    const float* __restrict__ resid,        // fp32 [M,768]
    float* __restrict__ out_f,              // fp32 [M,768]
    unsigned short* __restrict__ out_q,
    unsigned short* __restrict__ out_k,
    unsigned short* __restrict__ out_vT,
    unsigned short* __restrict__ out_bf)    // bf16 [M,N]
{
  const int nb = N >> 6;
  int n0 = (blockIdx.x % nb) << 6;
  int m0 = (blockIdx.x / nb) << 6;
  int tid = threadIdx.x;
  int wave = tid >> 6, lane = tid & 63;
  int quad = lane >> 4, l16 = lane & 15;
  int wm = (wave & 1) << 5, wn = (wave >> 1) << 5;

  __shared__ __align__(16) unsigned short As[64][40];
  __shared__ __align__(16) unsigned short Bs[64][40];

  f32x4 acc[2][2];
#pragma unroll
  for (int i = 0; i < 2; ++i)
#pragma unroll
    for (int j = 0; j < 2; ++j) acc[i][j] = (f32x4){0.f, 0.f, 0.f, 0.f};

  int lr = tid >> 2;          // 0..63
  int lc = (tid & 3) << 3;    // 0,8,16,24
  const unsigned short* ag = A + (size_t)(m0 + lr) * K + lc;
  const unsigned short* bg = Bt + (size_t)(n0 + lr) * K + lc;

  for (int k0 = 0; k0 < K; k0 += 32) {
    short8 av = *(const short8*)(ag + k0);
    short8 bv = *(const short8*)(bg + k0);
    __syncthreads();
    *(short8*)(&As[lr][lc]) = av;
    *(short8*)(&Bs[lr][lc]) = bv;
    __syncthreads();
    short8 af0 = *(const short8*)(&As[wm + l16][quad * 8]);
    short8 af1 = *(const short8*)(&As[wm + 16 + l16][quad * 8]);
    short8 bf0 = *(const short8*)(&Bs[wn + l16][quad * 8]);
    short8 bf1 = *(const short8*)(&Bs[wn + 16 + l16][quad * 8]);
    acc[0][0] = mfma16(af0, bf0, acc[0][0]);
    acc[0][1] = mfma16(af0, bf1, acc[0][1]);
    acc[1][0] = mfma16(af1, bf0, acc[1][0]);
    acc[1][1] = mfma16(af1, bf1, acc[1][1]);
  }

#pragma unroll
  for (int mt = 0; mt < 2; ++mt)
#pragma unroll
    for (int nt = 0; nt < 2; ++nt)
#pragma unroll
      for (int r = 0; r < 4; ++r) {
        int m = m0 + wm + mt * 16 + quad * 4 + r;
        int n = n0 + wn + nt * 16 + l16;
        float c = acc[mt][nt][r];
        if (MODE == MODE_QKV) {
          int bb = m >> 11, sIdx = m & 2047;
          if (n < 768) {
            float v = c + bias0[n];
            int hh = n >> 6, d = n & 63;
            out_q[(((size_t)(bb * NH + hh)) * SEQ + sIdx) * DH + d] = f2bf(v);
          } else if (n < 1536) {
            int nn = n - 768;
            float v = c + bias1[nn];
            int hh = nn >> 6, d = nn & 63;
            out_k[(((size_t)(bb * NH + hh)) * SEQ + sIdx) * DH + d] = f2bf(v);
          } else {
            int nn = n - 1536;
            float v = c + bias2[nn];
            int hh = nn >> 6, d = nn & 63;
            out_vT[(((size_t)(bb * NH + hh)) * DH + d) * SEQ + sIdx] = f2bf(v);
          }
        } else if (MODE == MODE_RESID) {
          out_f[(size_t)m * N + n] = resid[(size_t)m * N + n] + c + bias0[n];
        } else {  // MODE_GELU
          float t = c + bias0[n];
          float g = 0.5f * t * (1.0f + erff(t * 0.70710678118654752f));
          out_bf[(size_t)m * N + n] = f2bf(g);
        }
      }
}

// ---------------- fused attention: one block per (bh, 16 q-rows) ----------------
__global__ __launch_bounds__(256) void attn_kernel(
    const unsigned short* __restrict__ q,   // [B,NH,S,DH]
    const unsigned short* __restrict__ k,   // [B,NH,S,DH]
    const unsigned short* __restrict__ vT,  // [B,NH,DH,S]
    unsigned short* __restrict__ ctx)       // [MTOK,H] bf16
{
  const int SSTR = 2056;  // padded stride (+8 bf16) -> row stride 4112 B = 4 banks shift
  int bh = blockIdx.x >> 7;
  int q0 = (blockIdx.x & 127) << 4;
  int b = bh / NH, h = bh % NH;
  int tid = threadIdx.x;
  int wave = tid >> 6, lane = tid & 63;
  int quad = lane >> 4, l16 = lane & 15;

  __shared__ __align__(16) unsigned short Ss[16 * SSTR];
  __shared__ float red[256];
  __shared__ float rowmax[16];
  __shared__ float rowinv[16];

  const unsigned short* qp = q + ((size_t)bh * SEQ + q0) * DH;
  const unsigned short* kp = k + (size_t)bh * SEQ * DH;
  const unsigned short* vp = vT + (size_t)bh * DH * SEQ;

  // phase 1: scores strip [16 x 2048], each wave covers 512 keys
  short8 qf0 = *(const short8*)(qp + l16 * DH + quad * 8);
  short8 qf1 = *(const short8*)(qp + l16 * DH + 32 + quad * 8);
  int key_base = wave << 9;
  for (int kt = 0; kt < 512; kt += 16) {
    int key0 = key_base + kt;
    const unsigned short* krow = kp + (size_t)(key0 + l16) * DH;
    short8 kf0 = *(const short8*)(krow + quad * 8);
    short8 kf1 = *(const short8*)(krow + 32 + quad * 8);
    f32x4 sacc = {0.f, 0.f, 0.f, 0.f};
    sacc = mfma16(qf0, kf0, sacc);
    sacc = mfma16(qf1, kf1, sacc);
#pragma unroll
    for (int r = 0; r < 4; ++r)
      Ss[(quad * 4 + r) * SSTR + key0 + l16] = f2bf(sacc[r] * 0.125f);
  }
  __syncthreads();

  // phase 2: softmax (store unnormalized exp; fold 1/sum into epilogue)
  {
    int row = tid >> 4, cseg = tid & 15;
    unsigned short* srow = Ss + row * SSTR + cseg * 128;
    float pmax = -3.0e38f;
    for (int c = 0; c < 128; ++c) pmax = fmaxf(pmax, bf2f(srow[c]));
    red[tid] = pmax;
    __syncthreads();
    if (tid < 16) {
      float mx = -3.0e38f;
      for (int i = 0; i < 16; ++i) mx = fmaxf(mx, red[tid * 16 + i]);
      rowmax[tid] = mx;
    }
    __syncthreads();
    float rm = rowmax[row];
    float psum = 0.f;
    for (int c = 0; c < 128; ++c) {
      float p = __expf(bf2f(srow[c]) - rm);
      srow[c] = f2bf(p);
      psum += p;
    }
    red[tid] = psum;
    __syncthreads();
    if (tid < 16) {
      float sm = 0.f;
      for (int i = 0; i < 16; ++i) sm += red[tid * 16 + i];
      rowinv[tid] = 1.0f / sm;
    }
    __syncthreads();
  }

  // phase 3: ctx = P @ V; each wave owns one 16-wide d-tile, full 2048-key range
  f32x4 cacc = {0.f, 0.f, 0.f, 0.f};
  const unsigned short* vrow = vp + (size_t)(wave * 16 + l16) * SEQ;
  for (int kc = 0; kc < SEQ; kc += 32) {
    short8 pf = *(const short8*)(&Ss[l16 * SSTR + kc + quad * 8]);
    short8 vf = *(const short8*)(vrow + kc + quad * 8);
    cacc = mfma16(pf, vf, cacc);
  }
#pragma unroll
  for (int r = 0; r < 4; ++r) {
    int row = quad * 4 + r;
    float v = cacc[r] * rowinv[row];
    ctx[((size_t)(b * SEQ + q0 + row)) * H + h * DH + wave * 16 + l16] = f2bf(v);
  }
}

// ---------------- launch ----------------
extern "C" void kernel_launch(void* const* d_in, const int* in_sizes, int n_in,
                              void* d_out, int out_size, void* d_ws, size_t ws_size,
                              hipStream_t stream) {
  const float* latent = (const float*)d_in[0];
  const float* ln1_w = (const float*)d_in[1];
  const float* ln1_b = (const float*)d_in[2];
  const float* Wq = (const float*)d_in[3];
  const float* bq = (const float*)d_in[4];
  const float* Wk = (const float*)d_in[5];
  const float* bk = (const float*)d_in[6];
  const float* Wv = (const float*)d_in[7];
  const float* bv = (const float*)d_in[8];
  const float* Wo = (const float*)d_in[9];
  const float* bo = (const float*)d_in[10];
  const float* ln2_w = (const float*)d_in[11];
  const float* ln2_b = (const float*)d_in[12];
  const float* W1 = (const float*)d_in[13];
  const float* b1 = (const float*)d_in[14];
  const float* W2 = (const float*)d_in[15];
  const float* b2 = (const float*)d_in[16];
  float* out = (float*)d_out;

  char* ws = (char*)d_ws;
  unsigned short* WqkvT = (unsigned short*)ws; ws += (size_t)2304 * 768 * 2;
  unsigned short* WoT   = (unsigned short*)ws; ws += (size_t)768 * 768 * 2;
  unsigned short* W1T   = (unsigned short*)ws; ws += (size_t)3072 * 768 * 2;
  unsigned short* W2T   = (unsigned short*)ws; ws += (size_t)768 * 3072 * 2;
  unsigned short* nx    = (unsigned short*)ws; ws += (size_t)MTOK * H * 2;
  unsigned short* nx2   = (unsigned short*)ws; ws += (size_t)MTOK * H * 2;
  unsigned short* qb    = (unsigned short*)ws; ws += (size_t)MTOK * H * 2;
  unsigned short* kb    = (unsigned short*)ws; ws += (size_t)MTOK * H * 2;
  unsigned short* vTb   = (unsigned short*)ws; ws += (size_t)MTOK * H * 2;
  unsigned short* ctx   = (unsigned short*)ws; ws += (size_t)MTOK * H * 2;
  unsigned short* hbuf  = (unsigned short*)ws; ws += (size_t)MTOK * FF * 2;
  float* x1             = (float*)ws;          ws += (size_t)MTOK * H * 4;

  // weights -> bf16, transposed (B^T layout for GEMM); QKV packed into one [2304][768]
  transpose_cast<<<576, 256, 0, stream>>>(Wq, WqkvT, 768, 768);
  transpose_cast<<<576, 256, 0, stream>>>(Wk, WqkvT + (size_t)768 * 768, 768, 768);
  transpose_cast<<<576, 256, 0, stream>>>(Wv, WqkvT + (size_t)1536 * 768, 768, 768);
  transpose_cast<<<576, 256, 0, stream>>>(Wo, WoT, 768, 768);
  transpose_cast<<<2304, 256, 0, stream>>>(W1, W1T, 768, 3072);   // [768][3072] -> [3072][768]
  transpose_cast<<<2304, 256, 0, stream>>>(W2, W2T, 3072, 768);   // [3072][768] -> [768][3072]

  // LN1
  ln_kernel<<<MTOK, 256, 0, stream>>>(latent, ln1_w, ln1_b, nx);

  // QKV projection (fused, N=2304)
  gemm_kernel<MODE_QKV><<<64 * 36, 256, 0, stream>>>(
      nx, WqkvT, MTOK, 2304, 768, bq, bk, bv,
      nullptr, nullptr, qb, kb, vTb, nullptr);

  // attention
  attn_kernel<<<24 * 128, 256, 0, stream>>>(qb, kb, vTb, ctx);

  // output projection + residual -> x1 (fp32)
  gemm_kernel<MODE_RESID><<<64 * 12, 256, 0, stream>>>(
      ctx, WoT, MTOK, 768, 768, bo, nullptr, nullptr,
      latent, x1, nullptr, nullptr, nullptr, nullptr);

  // LN2
  ln_kernel<<<MTOK, 256, 0, stream>>>(x1, ln2_w, ln2_b, nx2);

  // FFN up + GELU -> hbuf (bf16)
  gemm_kernel<MODE_GELU><<<64 * 48, 256, 0, stream>>>(
      nx2, W1T, MTOK, 3072, 768, b1, nullptr, nullptr,
      nullptr, nullptr, nullptr, nullptr, nullptr, hbuf);

  // FFN down + residual -> d_out (fp32)
  gemm_kernel<MODE_RESID><<<64 * 12, 256, 0, stream>>>(
      hbuf, W2T, MTOK, 768, 3072, b2, nullptr, nullptr,
      x1, out, nullptr, nullptr, nullptr, nullptr);
}

// Round 2
// 471.121 us; speedup vs baseline: 1.1564x; 1.1564x over previous
//
#include <hip/hip_runtime.h>

#define H 768
#define FF 3072
#define NH 12
#define DH 64
#define SEQ 2048
#define MTOK 4096

typedef __attribute__((ext_vector_type(8))) short short8;
typedef __attribute__((ext_vector_type(4))) float f32x4;

__device__ __forceinline__ f32x4 mfma16(short8 a, short8 b, f32x4 c) {
  return __builtin_amdgcn_mfma_f32_16x16x32_bf16(a, b, c, 0, 0, 0);
}

__device__ __forceinline__ unsigned short f2bf(float f) {
  union { float f; unsigned int u; } c; c.f = f;
  unsigned int u = c.u;
  u += 0x7fffu + ((u >> 16) & 1u);  // round-to-nearest-even
  return (unsigned short)(u >> 16);
}
__device__ __forceinline__ float bf2f(unsigned short s) {
  union { unsigned int u; float f; } c; c.u = ((unsigned int)s) << 16;
  return c.f;
}
__device__ __forceinline__ unsigned int pk2bf(float lo, float hi) {
  return (unsigned int)f2bf(lo) | ((unsigned int)f2bf(hi) << 16);
}

// ---------------- transpose + cast: in fp32 [K][N] -> out bf16 [N][K] ----------------
__global__ __launch_bounds__(256) void transpose_cast(const float* __restrict__ in,
                                                      unsigned short* __restrict__ out,
                                                      int K, int N) {
  __shared__ float tile[32][33];
  int nb = N >> 5;
  int n0 = (blockIdx.x % nb) << 5;
  int k0 = (blockIdx.x / nb) << 5;
  int tx = threadIdx.x & 31, ty = threadIdx.x >> 5;  // ty 0..7
#pragma unroll
  for (int yy = 0; yy < 4; ++yy)
    tile[ty + yy * 8][tx] = in[(size_t)(k0 + ty + yy * 8) * N + n0 + tx];
  __syncthreads();
#pragma unroll
  for (int yy = 0; yy < 4; ++yy)
    out[(size_t)(n0 + ty + yy * 8) * K + k0 + tx] = f2bf(tile[tx][ty + yy * 8]);
}

// ---------------- LayerNorm fp32 [rows][768] -> bf16 ----------------
__global__ __launch_bounds__(256) void ln_kernel(const float* __restrict__ x,
                                                 const float* __restrict__ w,
                                                 const float* __restrict__ b,
                                                 unsigned short* __restrict__ out) {
  int row = blockIdx.x;
  int tid = threadIdx.x;
  const float* xr = x + (size_t)row * H;
  float v0 = xr[tid], v1 = xr[tid + 256], v2 = xr[tid + 512];
  float s = v0 + v1 + v2;
  float ss = v0 * v0 + v1 * v1 + v2 * v2;
#pragma unroll
  for (int off = 32; off > 0; off >>= 1) {
    s += __shfl_down(s, off);
    ss += __shfl_down(ss, off);
  }
  __shared__ float red[8];
  int wave = tid >> 6, lane = tid & 63;
  if (lane == 0) { red[wave] = s; red[4 + wave] = ss; }
  __syncthreads();
  s = red[0] + red[1] + red[2] + red[3];
  ss = red[4] + red[5] + red[6] + red[7];
  float mu = s * (1.0f / H);
  float var = ss * (1.0f / H) - mu * mu;
  float rs = rsqrtf(var + 1e-6f);
  unsigned short* orow = out + (size_t)row * H;
  orow[tid]       = f2bf((v0 - mu) * rs * w[tid]       + b[tid]);
  orow[tid + 256] = f2bf((v1 - mu) * rs * w[tid + 256] + b[tid + 256]);
  orow[tid + 512] = f2bf((v2 - mu) * rs * w[tid + 512] + b[tid + 512]);
}

// ---------------- GEMM: C[M,N] = A[M,K](bf16) @ Bt[N,K]^T(bf16), fused epilogues ----------------
enum { MODE_QKV = 0, MODE_RESID = 1, MODE_GELU = 2 };

template <int MODE>
__global__ __launch_bounds__(256) void gemm_kernel(
    const unsigned short* __restrict__ A,   // [M,K] bf16
    const unsigned short* __restrict__ Bt,  // [N,K] bf16
    int M, int N, int K,
    const float* __restrict__ bias0,
    const float* __restrict__ bias1,
    const float* __restrict__ bias2,
    const float* __restrict__ resid,        // fp32 [M,768]
    float* __restrict__ out_f,              // fp32 [M,768]
    unsigned short* __restrict__ out_q,
    unsigned short* __restrict__ out_k,
    unsigned short* __restrict__ out_vT,
    unsigned short* __restrict__ out_bf)    // bf16 [M,N]
{
  const int nb = N >> 6;
  int n0 = (blockIdx.x % nb) << 6;
  int m0 = (blockIdx.x / nb) << 6;
  int tid = threadIdx.x;
  int wave = tid >> 6, lane = tid & 63;
  int quad = lane >> 4, l16 = lane & 15;
  int wm = (wave & 1) << 5, wn = (wave >> 1) << 5;

  __shared__ __align__(16) unsigned short As[64][40];
  __shared__ __align__(16) unsigned short Bs[64][40];

  f32x4 acc[2][2];
#pragma unroll
  for (int i = 0; i < 2; ++i)
#pragma unroll
    for (int j = 0; j < 2; ++j) acc[i][j] = (f32x4){0.f, 0.f, 0.f, 0.f};

  int lr = tid >> 2;          // 0..63
  int lc = (tid & 3) << 3;    // 0,8,16,24
  const unsigned short* ag = A + (size_t)(m0 + lr) * K + lc;
  const unsigned short* bg = Bt + (size_t)(n0 + lr) * K + lc;

  for (int k0 = 0; k0 < K; k0 += 32) {
    short8 av = *(const short8*)(ag + k0);
    short8 bv = *(const short8*)(bg + k0);
    __syncthreads();
    *(short8*)(&As[lr][lc]) = av;
    *(short8*)(&Bs[lr][lc]) = bv;
    __syncthreads();
    short8 af0 = *(const short8*)(&As[wm + l16][quad * 8]);
    short8 af1 = *(const short8*)(&As[wm + 16 + l16][quad * 8]);
    short8 bf0 = *(const short8*)(&Bs[wn + l16][quad * 8]);
    short8 bf1 = *(const short8*)(&Bs[wn + 16 + l16][quad * 8]);
    acc[0][0] = mfma16(af0, bf0, acc[0][0]);
    acc[0][1] = mfma16(af0, bf1, acc[0][1]);
    acc[1][0] = mfma16(af1, bf0, acc[1][0]);
    acc[1][1] = mfma16(af1, bf1, acc[1][1]);
  }

#pragma unroll
  for (int mt = 0; mt < 2; ++mt)
#pragma unroll
    for (int nt = 0; nt < 2; ++nt)
#pragma unroll
      for (int r = 0; r < 4; ++r) {
        int m = m0 + wm + mt * 16 + quad * 4 + r;
        int n = n0 + wn + nt * 16 + l16;
        float c = acc[mt][nt][r];
        if (MODE == MODE_QKV) {
          int bb = m >> 11, sIdx = m & 2047;
          if (n < 768) {
            float v = c + bias0[n];
            int hh = n >> 6, d = n & 63;
            out_q[(((size_t)(bb * NH + hh)) * SEQ + sIdx) * DH + d] = f2bf(v);
          } else if (n < 1536) {
            int nn = n - 768;
            float v = c + bias1[nn];
            int hh = nn >> 6, d = nn & 63;
            out_k[(((size_t)(bb * NH + hh)) * SEQ + sIdx) * DH + d] = f2bf(v);
          } else {
            int nn = n - 1536;
            float v = c + bias2[nn];
            int hh = nn >> 6, d = nn & 63;
            out_vT[(((size_t)(bb * NH + hh)) * DH + d) * SEQ + sIdx] = f2bf(v);
          }
        } else if (MODE == MODE_RESID) {
          out_f[(size_t)m * N + n] = resid[(size_t)m * N + n] + c + bias0[n];
        } else {  // MODE_GELU
          float t = c + bias0[n];
          float g = 0.5f * t * (1.0f + erff(t * 0.70710678118654752f));
          out_bf[(size_t)m * N + n] = f2bf(g);
        }
      }
}

// ---------------- flash attention: register-resident, S^T trick, no LDS ----------------
// Block = 64 q-rows (4 waves x 16 q). Wave scans all 2048 keys in 32-key chunks.
// S^T = K·Q^T puts q on l16, keys on (quad,reg): softmax reduces are 2 shuffles,
// alpha and 1/l are lane-scalar. P^T B-frag built via ds_bpermute (wave-private).
__global__ __launch_bounds__(256) void flash_attn_kernel(
    const unsigned short* __restrict__ q,   // [B,NH,S,DH]
    const unsigned short* __restrict__ k,   // [B,NH,S,DH]
    const unsigned short* __restrict__ vT,  // [B,NH,DH,S]
    unsigned short* __restrict__ ctx)       // [MTOK,H] bf16
{
  int bh = blockIdx.x >> 5;          // 24 (b,h) pairs
  int qblk = blockIdx.x & 31;        // 32 q-blocks of 64
  int b = bh / NH, h = bh % NH;
  int tid = threadIdx.x;
  int wave = tid >> 6, lane = tid & 63;
  int quad = lane >> 4, l16 = lane & 15;
  int qrow = (qblk << 6) + (wave << 4);   // this wave's 16 q-rows

  const unsigned short* qp = q + ((size_t)bh * SEQ + qrow) * DH;
  const unsigned short* kp = k + (size_t)bh * SEQ * DH;
  const unsigned short* vp = vT + (size_t)bh * DH * SEQ;

  // Q as B operand: B[n=l16(q)][k=quad*8+j]
  short8 qf0 = *(const short8*)(qp + l16 * DH + quad * 8);
  short8 qf1 = *(const short8*)(qp + l16 * DH + 32 + quad * 8);

  f32x4 oacc[4];
#pragma unroll
  for (int dt = 0; dt < 4; ++dt) oacc[dt] = (f32x4){0.f, 0.f, 0.f, 0.f};
  float m_run = -3.0e38f;
  float l_run = 0.f;

  // bpermute source-lane addresses (x4 for byte addressing)
  int addrA = ((((2 * quad) & 3) << 4) + l16) << 2;
  int addrB = ((((2 * quad + 1) & 3) << 4) + l16) << 2;
  bool loquad = quad < 2;

  for (int key0 = 0; key0 < SEQ; key0 += 32) {
    const unsigned short* k0p = kp + (size_t)(key0 + l16) * DH;
    const unsigned short* k1p = kp + (size_t)(key0 + 16 + l16) * DH;
    short8 ka0 = *(const short8*)(k0p + quad * 8);
    short8 ka1 = *(const short8*)(k0p + 32 + quad * 8);
    short8 kb0 = *(const short8*)(k1p + quad * 8);
    short8 kb1 = *(const short8*)(k1p + 32 + quad * 8);
    // V B-frags: B[n=l16(d)][k=quad*8+j(key)]
    short8 vf0 = *(const short8*)(vp + (size_t)(0 * 16 + l16) * SEQ + key0 + quad * 8);
    short8 vf1 = *(const short8*)(vp + (size_t)(1 * 16 + l16) * SEQ + key0 + quad * 8);
    short8 vf2 = *(const short8*)(vp + (size_t)(2 * 16 + l16) * SEQ + key0 + quad * 8);
    short8 vf3 = *(const short8*)(vp + (size_t)(3 * 16 + l16) * SEQ + key0 + quad * 8);

    // S^T tiles: rows = keys (quad*4+reg), cols = q (l16)
    f32x4 s0 = (f32x4){0.f, 0.f, 0.f, 0.f};
    f32x4 s1 = (f32x4){0.f, 0.f, 0.f, 0.f};
    s0 = mfma16(ka0, qf0, s0);
    s0 = mfma16(ka1, qf1, s0);
    s1 = mfma16(kb0, qf0, s1);
    s1 = mfma16(kb1, qf1, s1);

    // column (q) max across 8 in-lane keys + quads
    float cmax = fmaxf(fmaxf(fmaxf(s0[0], s0[1]), fmaxf(s0[2], s0[3])),
                       fmaxf(fmaxf(s1[0], s1[1]), fmaxf(s1[2], s1[3])));
    cmax = fmaxf(cmax, __shfl_xor(cmax, 16));
    cmax = fmaxf(cmax, __shfl_xor(cmax, 32));
    cmax *= 0.125f;  // 1/sqrt(DH)
    float m_new = fmaxf(m_run, cmax);
    float alpha = __expf(m_run - m_new);
    m_run = m_new;

    f32x4 p0, p1;
#pragma unroll
    for (int r = 0; r < 4; ++r) {
      p0[r] = __expf(s0[r] * 0.125f - m_new);
      p1[r] = __expf(s1[r] * 0.125f - m_new);
    }
    float csum = (p0[0] + p0[1]) + (p0[2] + p0[3]) + (p1[0] + p1[1]) + (p1[2] + p1[3]);
    csum += __shfl_xor(csum, 16);
    csum += __shfl_xor(csum, 32);
    l_run = l_run * alpha + csum;

    // pack P^T to bf16 dwords: lo dword = keys 4q'+{0,1}, hi = 4q'+{2,3}
    int d00 = (int)pk2bf(p0[0], p0[1]);
    int d01 = (int)pk2bf(p0[2], p0[3]);
    int d10 = (int)pk2bf(p1[0], p1[1]);
    int d11 = (int)pk2bf(p1[2], p1[3]);

    // build P^T B-frag: lane(quad,l16) needs keys quad*8..quad*8+7, col l16
    int f0a = __builtin_amdgcn_ds_bpermute(addrA, d00);
    int f0b = __builtin_amdgcn_ds_bpermute(addrA, d10);
    int f1a = __builtin_amdgcn_ds_bpermute(addrA, d01);
    int f1b = __builtin_amdgcn_ds_bpermute(addrA, d11);
    int f2a = __builtin_amdgcn_ds_bpermute(addrB, d00);
    int f2b = __builtin_amdgcn_ds_bpermute(addrB, d10);
    int f3a = __builtin_amdgcn_ds_bpermute(addrB, d01);
    int f3b = __builtin_amdgcn_ds_bpermute(addrB, d11);
    union { short8 s; int i[4]; } pf;
    pf.i[0] = loquad ? f0a : f0b;
    pf.i[1] = loquad ? f1a : f1b;
    pf.i[2] = loquad ? f2a : f2b;
    pf.i[3] = loquad ? f3a : f3b;

    // O^T += V^T · P^T  (rows = d, cols = q)
#pragma unroll
    for (int r = 0; r < 4; ++r) {
      oacc[0][r] *= alpha; oacc[1][r] *= alpha;
      oacc[2][r] *= alpha; oacc[3][r] *= alpha;
    }
    oacc[0] = mfma16(vf0, pf.s, oacc[0]);
    oacc[1] = mfma16(vf1, pf.s, oacc[1]);
    oacc[2] = mfma16(vf2, pf.s, oacc[2]);
    oacc[3] = mfma16(vf3, pf.s, oacc[3]);
  }

  float rinv = 1.0f / l_run;
  unsigned short* crow = ctx + (size_t)(b * SEQ + qrow + l16) * H + h * DH;
#pragma unroll
  for (int dt = 0; dt < 4; ++dt) {
    unsigned int lo = pk2bf(oacc[dt][0] * rinv, oacc[dt][1] * rinv);
    unsigned int hi = pk2bf(oacc[dt][2] * rinv, oacc[dt][3] * rinv);
    uint2 pkt; pkt.x = lo; pkt.y = hi;
    *(uint2*)(crow + dt * 16 + quad * 4) = pkt;
  }
}

// ---------------- launch ----------------
extern "C" void kernel_launch(void* const* d_in, const int* in_sizes, int n_in,
                              void* d_out, int out_size, void* d_ws, size_t ws_size,
                              hipStream_t stream) {
  const float* latent = (const float*)d_in[0];
  const float* ln1_w = (const float*)d_in[1];
  const float* ln1_b = (const float*)d_in[2];
  const float* Wq = (const float*)d_in[3];
  const float* bq = (const float*)d_in[4];
  const float* Wk = (const float*)d_in[5];
  const float* bk = (const float*)d_in[6];
  const float* Wv = (const float*)d_in[7];
  const float* bv = (const float*)d_in[8];
  const float* Wo = (const float*)d_in[9];
  const float* bo = (const float*)d_in[10];
  const float* ln2_w = (const float*)d_in[11];
  const float* ln2_b = (const float*)d_in[12];
  const float* W1 = (const float*)d_in[13];
  const float* b1 = (const float*)d_in[14];
  const float* W2 = (const float*)d_in[15];
  const float* b2 = (const float*)d_in[16];
  float* out = (float*)d_out;

  char* ws = (char*)d_ws;
  unsigned short* WqkvT = (unsigned short*)ws; ws += (size_t)2304 * 768 * 2;
  unsigned short* WoT   = (unsigned short*)ws; ws += (size_t)768 * 768 * 2;
  unsigned short* W1T   = (unsigned short*)ws; ws += (size_t)3072 * 768 * 2;
  unsigned short* W2T   = (unsigned short*)ws; ws += (size_t)768 * 3072 * 2;
  unsigned short* nx    = (unsigned short*)ws; ws += (size_t)MTOK * H * 2;
  unsigned short* nx2   = (unsigned short*)ws; ws += (size_t)MTOK * H * 2;
  unsigned short* qb    = (unsigned short*)ws; ws += (size_t)MTOK * H * 2;
  unsigned short* kb    = (unsigned short*)ws; ws += (size_t)MTOK * H * 2;
  unsigned short* vTb   = (unsigned short*)ws; ws += (size_t)MTOK * H * 2;
  unsigned short* ctx   = (unsigned short*)ws; ws += (size_t)MTOK * H * 2;
  unsigned short* hbuf  = (unsigned short*)ws; ws += (size_t)MTOK * FF * 2;
  float* x1             = (float*)ws;          ws += (size_t)MTOK * H * 4;

  // weights -> bf16, transposed (B^T layout for GEMM); QKV packed into one [2304][768]
  transpose_cast<<<576, 256, 0, stream>>>(Wq, WqkvT, 768, 768);
  transpose_cast<<<576, 256, 0, stream>>>(Wk, WqkvT + (size_t)768 * 768, 768, 768);
  transpose_cast<<<576, 256, 0, stream>>>(Wv, WqkvT + (size_t)1536 * 768, 768, 768);
  transpose_cast<<<576, 256, 0, stream>>>(Wo, WoT, 768, 768);
  transpose_cast<<<2304, 256, 0, stream>>>(W1, W1T, 768, 3072);   // [768][3072] -> [3072][768]
  transpose_cast<<<2304, 256, 0, stream>>>(W2, W2T, 3072, 768);   // [3072][768] -> [768][3072]

  // LN1
  ln_kernel<<<MTOK, 256, 0, stream>>>(latent, ln1_w, ln1_b, nx);

  // QKV projection (fused, N=2304)
  gemm_kernel<MODE_QKV><<<64 * 36, 256, 0, stream>>>(
      nx, WqkvT, MTOK, 2304, 768, bq, bk, bv,
      nullptr, nullptr, qb, kb, vTb, nullptr);

  // attention (flash, register-resident)
  flash_attn_kernel<<<24 * 32, 256, 0, stream>>>(qb, kb, vTb, ctx);

  // output projection + residual -> x1 (fp32)
  gemm_kernel<MODE_RESID><<<64 * 12, 256, 0, stream>>>(
      ctx, WoT, MTOK, 768, 768, bo, nullptr, nullptr,
      latent, x1, nullptr, nullptr, nullptr, nullptr);

  // LN2
  ln_kernel<<<MTOK, 256, 0, stream>>>(x1, ln2_w, ln2_b, nx2);

  // FFN up + GELU -> hbuf (bf16)
  gemm_kernel<MODE_GELU><<<64 * 48, 256, 0, stream>>>(
      nx2, W1T, MTOK, 3072, 768, b1, nullptr, nullptr,
      nullptr, nullptr, nullptr, nullptr, nullptr, hbuf);

  // FFN down + residual -> d_out (fp32)
  gemm_kernel<MODE_RESID><<<64 * 12, 256, 0, stream>>>(
      hbuf, W2T, MTOK, 768, 3072, b2, nullptr, nullptr,
      x1, out, nullptr, nullptr, nullptr, nullptr);
}

// Round 3
// 395.221 us; speedup vs baseline: 1.3785x; 1.1920x over previous
//
#include <hip/hip_runtime.h>

#define H 768
#define FF 3072
#define NH 12
#define DH 64
#define SEQ 2048
#define MTOK 4096

typedef __attribute__((ext_vector_type(8))) short short8;
typedef __attribute__((ext_vector_type(4))) float f32x4;

__device__ __forceinline__ f32x4 mfma16(short8 a, short8 b, f32x4 c) {
  return __builtin_amdgcn_mfma_f32_16x16x32_bf16(a, b, c, 0, 0, 0);
}

__device__ __forceinline__ unsigned short f2bf(float f) {
  union { float f; unsigned int u; } c; c.f = f;
  unsigned int u = c.u;
  u += 0x7fffu + ((u >> 16) & 1u);  // round-to-nearest-even
  return (unsigned short)(u >> 16);
}
__device__ __forceinline__ float bf2f(unsigned short s) {
  union { unsigned int u; float f; } c; c.u = ((unsigned int)s) << 16;
  return c.f;
}
__device__ __forceinline__ unsigned int pk2bf(float lo, float hi) {
  return (unsigned int)f2bf(lo) | ((unsigned int)f2bf(hi) << 16);
}
// truncating bf16 pair pack: one v_perm_b32
__device__ __forceinline__ unsigned int pktrunc(float lo, float hi) {
  union { float f; unsigned int u; } a, b; a.f = hi; b.f = lo;
  return __builtin_amdgcn_perm(a.u, b.u, 0x07060302u);
}

// ---------------- transpose + cast: in fp32 [K][N] -> out bf16 [N][K] ----------------
__global__ __launch_bounds__(256) void transpose_cast(const float* __restrict__ in,
                                                      unsigned short* __restrict__ out,
                                                      int K, int N) {
  __shared__ float tile[32][33];
  int nb = N >> 5;
  int n0 = (blockIdx.x % nb) << 5;
  int k0 = (blockIdx.x / nb) << 5;
  int tx = threadIdx.x & 31, ty = threadIdx.x >> 5;  // ty 0..7
#pragma unroll
  for (int yy = 0; yy < 4; ++yy)
    tile[ty + yy * 8][tx] = in[(size_t)(k0 + ty + yy * 8) * N + n0 + tx];
  __syncthreads();
#pragma unroll
  for (int yy = 0; yy < 4; ++yy)
    out[(size_t)(n0 + ty + yy * 8) * K + k0 + tx] = f2bf(tile[tx][ty + yy * 8]);
}

// ---------------- LayerNorm fp32 [rows][768] -> bf16 ----------------
__global__ __launch_bounds__(256) void ln_kernel(const float* __restrict__ x,
                                                 const float* __restrict__ w,
                                                 const float* __restrict__ b,
                                                 unsigned short* __restrict__ out) {
  int row = blockIdx.x;
  int tid = threadIdx.x;
  const float* xr = x + (size_t)row * H;
  float v0 = xr[tid], v1 = xr[tid + 256], v2 = xr[tid + 512];
  float s = v0 + v1 + v2;
  float ss = v0 * v0 + v1 * v1 + v2 * v2;
#pragma unroll
  for (int off = 32; off > 0; off >>= 1) {
    s += __shfl_down(s, off);
    ss += __shfl_down(ss, off);
  }
  __shared__ float red[8];
  int wave = tid >> 6, lane = tid & 63;
  if (lane == 0) { red[wave] = s; red[4 + wave] = ss; }
  __syncthreads();
  s = red[0] + red[1] + red[2] + red[3];
  ss = red[4] + red[5] + red[6] + red[7];
  float mu = s * (1.0f / H);
  float var = ss * (1.0f / H) - mu * mu;
  float rs = rsqrtf(var + 1e-6f);
  unsigned short* orow = out + (size_t)row * H;
  orow[tid]       = f2bf((v0 - mu) * rs * w[tid]       + b[tid]);
  orow[tid + 256] = f2bf((v1 - mu) * rs * w[tid + 256] + b[tid + 256]);
  orow[tid + 512] = f2bf((v2 - mu) * rs * w[tid + 512] + b[tid + 512]);
}

// ---------------- GEMM: C[M,N] = A[M,K](bf16) @ Bt[N,K]^T(bf16), fused epilogues ----------------
enum { MODE_QKV = 0, MODE_RESID = 1, MODE_GELU = 2 };

template <int MODE>
__global__ __launch_bounds__(256) void gemm_kernel(
    const unsigned short* __restrict__ A,   // [M,K] bf16
    const unsigned short* __restrict__ Bt,  // [N,K] bf16
    int M, int N, int K,
    const float* __restrict__ bias0,
    const float* __restrict__ bias1,
    const float* __restrict__ bias2,
    const float* __restrict__ resid,        // fp32 [M,768]
    float* __restrict__ out_f,              // fp32 [M,768]
    unsigned short* __restrict__ out_q,
    unsigned short* __restrict__ out_k,
    unsigned short* __restrict__ out_vT,
    unsigned short* __restrict__ out_bf)    // bf16 [M,N]
{
  const int nb = N >> 6;
  int n0 = (blockIdx.x % nb) << 6;
  int m0 = (blockIdx.x / nb) << 6;
  int tid = threadIdx.x;
  int wave = tid >> 6, lane = tid & 63;
  int quad = lane >> 4, l16 = lane & 15;
  int wm = (wave & 1) << 5, wn = (wave >> 1) << 5;

  __shared__ __align__(16) unsigned short As[64][40];
  __shared__ __align__(16) unsigned short Bs[64][40];

  f32x4 acc[2][2];
#pragma unroll
  for (int i = 0; i < 2; ++i)
#pragma unroll
    for (int j = 0; j < 2; ++j) acc[i][j] = (f32x4){0.f, 0.f, 0.f, 0.f};

  int lr = tid >> 2;          // 0..63
  int lc = (tid & 3) << 3;    // 0,8,16,24
  const unsigned short* ag = A + (size_t)(m0 + lr) * K + lc;
  const unsigned short* bg = Bt + (size_t)(n0 + lr) * K + lc;

  for (int k0 = 0; k0 < K; k0 += 32) {
    short8 av = *(const short8*)(ag + k0);
    short8 bv = *(const short8*)(bg + k0);
    __syncthreads();
    *(short8*)(&As[lr][lc]) = av;
    *(short8*)(&Bs[lr][lc]) = bv;
    __syncthreads();
    short8 af0 = *(const short8*)(&As[wm + l16][quad * 8]);
    short8 af1 = *(const short8*)(&As[wm + 16 + l16][quad * 8]);
    short8 bf0 = *(const short8*)(&Bs[wn + l16][quad * 8]);
    short8 bf1 = *(const short8*)(&Bs[wn + 16 + l16][quad * 8]);
    acc[0][0] = mfma16(af0, bf0, acc[0][0]);
    acc[0][1] = mfma16(af0, bf1, acc[0][1]);
    acc[1][0] = mfma16(af1, bf0, acc[1][0]);
    acc[1][1] = mfma16(af1, bf1, acc[1][1]);
  }

#pragma unroll
  for (int mt = 0; mt < 2; ++mt)
#pragma unroll
    for (int nt = 0; nt < 2; ++nt)
#pragma unroll
      for (int r = 0; r < 4; ++r) {
        int m = m0 + wm + mt * 16 + quad * 4 + r;
        int n = n0 + wn + nt * 16 + l16;
        float c = acc[mt][nt][r];
        if (MODE == MODE_QKV) {
          int bb = m >> 11, sIdx = m & 2047;
          if (n < 768) {
            float v = c + bias0[n];
            int hh = n >> 6, d = n & 63;
            out_q[(((size_t)(bb * NH + hh)) * SEQ + sIdx) * DH + d] = f2bf(v);
          } else if (n < 1536) {
            int nn = n - 768;
            float v = c + bias1[nn];
            int hh = nn >> 6, d = nn & 63;
            out_k[(((size_t)(bb * NH + hh)) * SEQ + sIdx) * DH + d] = f2bf(v);
          } else {
            int nn = n - 1536;
            float v = c + bias2[nn];
            int hh = nn >> 6, d = nn & 63;
            out_vT[(((size_t)(bb * NH + hh)) * DH + d) * SEQ + sIdx] = f2bf(v);
          }
        } else if (MODE == MODE_RESID) {
          out_f[(size_t)m * N + n] = resid[(size_t)m * N + n] + c + bias0[n];
        } else {  // MODE_GELU
          float t = c + bias0[n];
          float g = 0.5f * t * (1.0f + erff(t * 0.70710678118654752f));
          out_bf[(size_t)m * N + n] = f2bf(g);
        }
      }
}

// ---------------- flash attention v3: key-split + combine ----------------
// Block = 32 q-rows, 4 waves; wave w scans keys [w*512,(w+1)*512) over 2 q-tiles.
// S^T = K·Q^T (q on l16): softmax reduce = 2 shfl, m/l lane-scalar per q-tile.
// exp2-domain online softmax; P^T B-frag via ds_bpermute; partial (m,l,O)
// combined across the 4 waves through LDS at the end.
__global__ __launch_bounds__(256, 4) void flash_attn_kernel(
    const unsigned short* __restrict__ q,   // [B,NH,S,DH]
    const unsigned short* __restrict__ k,   // [B,NH,S,DH]
    const unsigned short* __restrict__ vT,  // [B,NH,DH,S]
    unsigned short* __restrict__ ctx)       // [MTOK,H] bf16
{
  const float CEXP = 0.18033688011112042f;  // 0.125 * log2(e)
  int bh = blockIdx.x >> 6;          // 24 (b,h)
  int qblk = blockIdx.x & 63;        // 64 q-blocks of 32
  int b = bh / NH, h = bh % NH;
  int tid = threadIdx.x;
  int wave = tid >> 6, lane = tid & 63;
  int quad = lane >> 4, l16 = lane & 15;
  int qbase = qblk << 5;

  const unsigned short* qp = q + ((size_t)bh * SEQ + qbase) * DH;
  const unsigned short* kp = k + (size_t)bh * SEQ * DH;
  const unsigned short* vp = vT + (size_t)bh * DH * SEQ;

  // Q B-frags for two 16-row q-tiles
  short8 qf00 = *(const short8*)(qp + l16 * DH + quad * 8);
  short8 qf01 = *(const short8*)(qp + l16 * DH + 32 + quad * 8);
  short8 qf10 = *(const short8*)(qp + (16 + l16) * DH + quad * 8);
  short8 qf11 = *(const short8*)(qp + (16 + l16) * DH + 32 + quad * 8);

  f32x4 oacc[2][4];
#pragma unroll
  for (int t = 0; t < 2; ++t)
#pragma unroll
    for (int dt = 0; dt < 4; ++dt) oacc[t][dt] = (f32x4){0.f, 0.f, 0.f, 0.f};
  float M[2] = {-3.0e38f, -3.0e38f};  // running max, log2 domain
  float L[2] = {0.f, 0.f};

  int addrA = ((((2 * quad) & 3) << 4) + l16) << 2;
  int addrB = ((((2 * quad + 1) & 3) << 4) + l16) << 2;
  bool loquad = quad < 2;

  int keylo = wave << 9;
  for (int key0 = keylo; key0 < keylo + 512; key0 += 32) {
    const unsigned short* k0p = kp + (size_t)(key0 + l16) * DH;
    const unsigned short* k1p = kp + (size_t)(key0 + 16 + l16) * DH;
    short8 ka0 = *(const short8*)(k0p + quad * 8);
    short8 ka1 = *(const short8*)(k0p + 32 + quad * 8);
    short8 kb0 = *(const short8*)(k1p + quad * 8);
    short8 kb1 = *(const short8*)(k1p + 32 + quad * 8);
    short8 vf0 = *(const short8*)(vp + (size_t)(0 * 16 + l16) * SEQ + key0 + quad * 8);
    short8 vf1 = *(const short8*)(vp + (size_t)(1 * 16 + l16) * SEQ + key0 + quad * 8);
    short8 vf2 = *(const short8*)(vp + (size_t)(2 * 16 + l16) * SEQ + key0 + quad * 8);
    short8 vf3 = *(const short8*)(vp + (size_t)(3 * 16 + l16) * SEQ + key0 + quad * 8);

#pragma unroll
    for (int t = 0; t < 2; ++t) {
      short8 q0 = t ? qf10 : qf00;
      short8 q1 = t ? qf11 : qf01;
      f32x4 s0 = (f32x4){0.f, 0.f, 0.f, 0.f};
      f32x4 s1 = (f32x4){0.f, 0.f, 0.f, 0.f};
      s0 = mfma16(ka0, q0, s0);
      s0 = mfma16(ka1, q1, s0);
      s1 = mfma16(kb0, q0, s1);
      s1 = mfma16(kb1, q1, s1);

      float cmax = fmaxf(fmaxf(fmaxf(s0[0], s0[1]), fmaxf(s0[2], s0[3])),
                         fmaxf(fmaxf(s1[0], s1[1]), fmaxf(s1[2], s1[3])));
      cmax = fmaxf(cmax, __shfl_xor(cmax, 16));
      cmax = fmaxf(cmax, __shfl_xor(cmax, 32));
      float m_new = fmaxf(M[t], cmax * CEXP);
      float alpha = __builtin_amdgcn_exp2f(M[t] - m_new);
      M[t] = m_new;

      f32x4 p0, p1;
#pragma unroll
      for (int r = 0; r < 4; ++r) {
        p0[r] = __builtin_amdgcn_exp2f(s0[r] * CEXP - m_new);
        p1[r] = __builtin_amdgcn_exp2f(s1[r] * CEXP - m_new);
      }
      float csum = (p0[0] + p0[1]) + (p0[2] + p0[3]) + (p1[0] + p1[1]) + (p1[2] + p1[3]);
      csum += __shfl_xor(csum, 16);
      csum += __shfl_xor(csum, 32);
      L[t] = L[t] * alpha + csum;

      int d00 = (int)pktrunc(p0[0], p0[1]);
      int d01 = (int)pktrunc(p0[2], p0[3]);
      int d10 = (int)pktrunc(p1[0], p1[1]);
      int d11 = (int)pktrunc(p1[2], p1[3]);

      int f0a = __builtin_amdgcn_ds_bpermute(addrA, d00);
      int f0b = __builtin_amdgcn_ds_bpermute(addrA, d10);
      int f1a = __builtin_amdgcn_ds_bpermute(addrA, d01);
      int f1b = __builtin_amdgcn_ds_bpermute(addrA, d11);
      int f2a = __builtin_amdgcn_ds_bpermute(addrB, d00);
      int f2b = __builtin_amdgcn_ds_bpermute(addrB, d10);
      int f3a = __builtin_amdgcn_ds_bpermute(addrB, d01);
      int f3b = __builtin_amdgcn_ds_bpermute(addrB, d11);
      union { short8 s; int i[4]; } pf;
      pf.i[0] = loquad ? f0a : f0b;
      pf.i[1] = loquad ? f1a : f1b;
      pf.i[2] = loquad ? f2a : f2b;
      pf.i[3] = loquad ? f3a : f3b;

#pragma unroll
      for (int dt = 0; dt < 4; ++dt)
#pragma unroll
        for (int r = 0; r < 4; ++r) oacc[t][dt][r] *= alpha;
      oacc[t][0] = mfma16(vf0, pf.s, oacc[t][0]);
      oacc[t][1] = mfma16(vf1, pf.s, oacc[t][1]);
      oacc[t][2] = mfma16(vf2, pf.s, oacc[t][2]);
      oacc[t][3] = mfma16(vf3, pf.s, oacc[t][3]);
    }
  }

  // ---- combine partials across the 4 key-split waves ----
  __shared__ float mbuf[4][2][16];
  __shared__ float lbuf[4][2][16];
  __shared__ uint2 obuf[4][2][4][64];

  if (lane < 16) {
    mbuf[wave][0][lane] = M[0];
    mbuf[wave][1][lane] = M[1];
  }
  __syncthreads();
#pragma unroll
  for (int t = 0; t < 2; ++t) {
    float m0 = mbuf[0][t][l16], m1 = mbuf[1][t][l16];
    float m2 = mbuf[2][t][l16], m3 = mbuf[3][t][l16];
    float mstar = fmaxf(fmaxf(m0, m1), fmaxf(m2, m3));
    float coef = __builtin_amdgcn_exp2f(M[t] - mstar);
    if (lane < 16) lbuf[wave][t][lane] = L[t] * coef;
#pragma unroll
    for (int dt = 0; dt < 4; ++dt) {
      uint2 pk;
      pk.x = pk2bf(oacc[t][dt][0] * coef, oacc[t][dt][1] * coef);
      pk.y = pk2bf(oacc[t][dt][2] * coef, oacc[t][dt][3] * coef);
      obuf[wave][t][dt][lane] = pk;
    }
  }
  __syncthreads();

#pragma unroll
  for (int pp = 0; pp < 2; ++pp) {
    int pi = wave * 2 + pp;
    int t = pi >> 2, dt = pi & 3;
    f32x4 sum = (f32x4){0.f, 0.f, 0.f, 0.f};
#pragma unroll
    for (int w = 0; w < 4; ++w) {
      uint2 pk = obuf[w][t][dt][lane];
      sum[0] += bf2f((unsigned short)(pk.x & 0xffff));
      sum[1] += bf2f((unsigned short)(pk.x >> 16));
      sum[2] += bf2f((unsigned short)(pk.y & 0xffff));
      sum[3] += bf2f((unsigned short)(pk.y >> 16));
    }
    float lstar = lbuf[0][t][l16] + lbuf[1][t][l16] + lbuf[2][t][l16] + lbuf[3][t][l16];
    float rinv = 1.0f / lstar;
    uint2 res;
    res.x = pk2bf(sum[0] * rinv, sum[1] * rinv);
    res.y = pk2bf(sum[2] * rinv, sum[3] * rinv);
    unsigned short* crow = ctx + (size_t)(b * SEQ + qbase + t * 16 + l16) * H
                           + h * DH + dt * 16 + quad * 4;
    *(uint2*)crow = res;
  }
}

// ---------------- launch ----------------
extern "C" void kernel_launch(void* const* d_in, const int* in_sizes, int n_in,
                              void* d_out, int out_size, void* d_ws, size_t ws_size,
                              hipStream_t stream) {
  const float* latent = (const float*)d_in[0];
  const float* ln1_w = (const float*)d_in[1];
  const float* ln1_b = (const float*)d_in[2];
  const float* Wq = (const float*)d_in[3];
  const float* bq = (const float*)d_in[4];
  const float* Wk = (const float*)d_in[5];
  const float* bk = (const float*)d_in[6];
  const float* Wv = (const float*)d_in[7];
  const float* bv = (const float*)d_in[8];
  const float* Wo = (const float*)d_in[9];
  const float* bo = (const float*)d_in[10];
  const float* ln2_w = (const float*)d_in[11];
  const float* ln2_b = (const float*)d_in[12];
  const float* W1 = (const float*)d_in[13];
  const float* b1 = (const float*)d_in[14];
  const float* W2 = (const float*)d_in[15];
  const float* b2 = (const float*)d_in[16];
  float* out = (float*)d_out;

  char* ws = (char*)d_ws;
  unsigned short* WqkvT = (unsigned short*)ws; ws += (size_t)2304 * 768 * 2;
  unsigned short* WoT   = (unsigned short*)ws; ws += (size_t)768 * 768 * 2;
  unsigned short* W1T   = (unsigned short*)ws; ws += (size_t)3072 * 768 * 2;
  unsigned short* W2T   = (unsigned short*)ws; ws += (size_t)768 * 3072 * 2;
  unsigned short* nx    = (unsigned short*)ws; ws += (size_t)MTOK * H * 2;
  unsigned short* nx2   = (unsigned short*)ws; ws += (size_t)MTOK * H * 2;
  unsigned short* qb    = (unsigned short*)ws; ws += (size_t)MTOK * H * 2;
  unsigned short* kb    = (unsigned short*)ws; ws += (size_t)MTOK * H * 2;
  unsigned short* vTb   = (unsigned short*)ws; ws += (size_t)MTOK * H * 2;
  unsigned short* ctx   = (unsigned short*)ws; ws += (size_t)MTOK * H * 2;
  unsigned short* hbuf  = (unsigned short*)ws; ws += (size_t)MTOK * FF * 2;
  float* x1             = (float*)ws;          ws += (size_t)MTOK * H * 4;

  // weights -> bf16, transposed (B^T layout for GEMM); QKV packed into one [2304][768]
  transpose_cast<<<576, 256, 0, stream>>>(Wq, WqkvT, 768, 768);
  transpose_cast<<<576, 256, 0, stream>>>(Wk, WqkvT + (size_t)768 * 768, 768, 768);
  transpose_cast<<<576, 256, 0, stream>>>(Wv, WqkvT + (size_t)1536 * 768, 768, 768);
  transpose_cast<<<576, 256, 0, stream>>>(Wo, WoT, 768, 768);
  transpose_cast<<<2304, 256, 0, stream>>>(W1, W1T, 768, 3072);   // [768][3072] -> [3072][768]
  transpose_cast<<<2304, 256, 0, stream>>>(W2, W2T, 3072, 768);   // [3072][768] -> [768][3072]

  // LN1
  ln_kernel<<<MTOK, 256, 0, stream>>>(latent, ln1_w, ln1_b, nx);

  // QKV projection (fused, N=2304)
  gemm_kernel<MODE_QKV><<<64 * 36, 256, 0, stream>>>(
      nx, WqkvT, MTOK, 2304, 768, bq, bk, bv,
      nullptr, nullptr, qb, kb, vTb, nullptr);

  // attention (flash, key-split + combine)
  flash_attn_kernel<<<24 * 64, 256, 0, stream>>>(qb, kb, vTb, ctx);

  // output projection + residual -> x1 (fp32)
  gemm_kernel<MODE_RESID><<<64 * 12, 256, 0, stream>>>(
      ctx, WoT, MTOK, 768, 768, bo, nullptr, nullptr,
      latent, x1, nullptr, nullptr, nullptr, nullptr);

  // LN2
  ln_kernel<<<MTOK, 256, 0, stream>>>(x1, ln2_w, ln2_b, nx2);

  // FFN up + GELU -> hbuf (bf16)
  gemm_kernel<MODE_GELU><<<64 * 48, 256, 0, stream>>>(
      nx2, W1T, MTOK, 3072, 768, b1, nullptr, nullptr,
      nullptr, nullptr, nullptr, nullptr, nullptr, hbuf);

  // FFN down + residual -> d_out (fp32)
  gemm_kernel<MODE_RESID><<<64 * 12, 256, 0, stream>>>(
      hbuf, W2T, MTOK, 768, 3072, b2, nullptr, nullptr,
      x1, out, nullptr, nullptr, nullptr, nullptr);
}

// Round 4
// 371.710 us; speedup vs baseline: 1.4657x; 1.0632x over previous
//
#include <hip/hip_runtime.h>

#define H 768
#define FF 3072
#define NH 12
#define DH 64
#define SEQ 2048
#define MTOK 4096

typedef __attribute__((ext_vector_type(8))) short short8;
typedef __attribute__((ext_vector_type(4))) float f32x4;

__device__ __forceinline__ f32x4 mfma16(short8 a, short8 b, f32x4 c) {
  return __builtin_amdgcn_mfma_f32_16x16x32_bf16(a, b, c, 0, 0, 0);
}

__device__ __forceinline__ unsigned short f2bf(float f) {
  union { float f; unsigned int u; } c; c.f = f;
  unsigned int u = c.u;
  u += 0x7fffu + ((u >> 16) & 1u);  // round-to-nearest-even
  return (unsigned short)(u >> 16);
}
__device__ __forceinline__ float bf2f(unsigned short s) {
  union { unsigned int u; float f; } c; c.u = ((unsigned int)s) << 16;
  return c.f;
}
__device__ __forceinline__ unsigned int pk2bf(float lo, float hi) {
  return (unsigned int)f2bf(lo) | ((unsigned int)f2bf(hi) << 16);
}
// truncating bf16 pair pack: one v_perm_b32
__device__ __forceinline__ unsigned int pktrunc(float lo, float hi) {
  union { float f; unsigned int u; } a, b; a.f = hi; b.f = lo;
  return __builtin_amdgcn_perm(a.u, b.u, 0x07060302u);
}

// async global->LDS, 16B per lane; LDS dest = wave-uniform base + lane*16
__device__ __forceinline__ void gld16(const unsigned short* g, unsigned short* l) {
  __builtin_amdgcn_global_load_lds(
      (const __attribute__((address_space(1))) void*)g,
      (__attribute__((address_space(3))) void*)l, 16, 0, 0);
}

// ---------------- transpose + cast: in fp32 [K][N] -> out bf16 [N][K] ----------------
__global__ __launch_bounds__(256) void transpose_cast(const float* __restrict__ in,
                                                      unsigned short* __restrict__ out,
                                                      int K, int N) {
  __shared__ float tile[32][33];
  int nb = N >> 5;
  int n0 = (blockIdx.x % nb) << 5;
  int k0 = (blockIdx.x / nb) << 5;
  int tx = threadIdx.x & 31, ty = threadIdx.x >> 5;  // ty 0..7
#pragma unroll
  for (int yy = 0; yy < 4; ++yy)
    tile[ty + yy * 8][tx] = in[(size_t)(k0 + ty + yy * 8) * N + n0 + tx];
  __syncthreads();
#pragma unroll
  for (int yy = 0; yy < 4; ++yy)
    out[(size_t)(n0 + ty + yy * 8) * K + k0 + tx] = f2bf(tile[tx][ty + yy * 8]);
}

// ---------------- LayerNorm fp32 [rows][768] -> bf16 ----------------
__global__ __launch_bounds__(256) void ln_kernel(const float* __restrict__ x,
                                                 const float* __restrict__ w,
                                                 const float* __restrict__ b,
                                                 unsigned short* __restrict__ out) {
  int row = blockIdx.x;
  int tid = threadIdx.x;
  const float* xr = x + (size_t)row * H;
  float v0 = xr[tid], v1 = xr[tid + 256], v2 = xr[tid + 512];
  float s = v0 + v1 + v2;
  float ss = v0 * v0 + v1 * v1 + v2 * v2;
#pragma unroll
  for (int off = 32; off > 0; off >>= 1) {
    s += __shfl_down(s, off);
    ss += __shfl_down(ss, off);
  }
  __shared__ float red[8];
  int wave = tid >> 6, lane = tid & 63;
  if (lane == 0) { red[wave] = s; red[4 + wave] = ss; }
  __syncthreads();
  s = red[0] + red[1] + red[2] + red[3];
  ss = red[4] + red[5] + red[6] + red[7];
  float mu = s * (1.0f / H);
  float var = ss * (1.0f / H) - mu * mu;
  float rs = rsqrtf(var + 1e-6f);
  unsigned short* orow = out + (size_t)row * H;
  orow[tid]       = f2bf((v0 - mu) * rs * w[tid]       + b[tid]);
  orow[tid + 256] = f2bf((v1 - mu) * rs * w[tid + 256] + b[tid + 256]);
  orow[tid + 512] = f2bf((v2 - mu) * rs * w[tid + 512] + b[tid + 512]);
}

// ---------------- GEMM m97-style: 128 x TN tile, BK=32, global_load_lds w16 ----------------
enum { MODE_QKV = 0, MODE_RESID = 1, MODE_GELU = 2 };

template <int MODE, int TN>
__global__ __launch_bounds__(256) void gemm128(
    const unsigned short* __restrict__ A,   // [M,K] bf16
    const unsigned short* __restrict__ Bt,  // [N,K] bf16
    int M, int N, int K,
    const float* __restrict__ bias0,
    const float* __restrict__ bias1,
    const float* __restrict__ bias2,
    const float* __restrict__ resid,        // fp32 [M,N]
    float* __restrict__ out_f,              // fp32 [M,N]
    unsigned short* __restrict__ out_q,
    unsigned short* __restrict__ out_k,
    unsigned short* __restrict__ out_vT,
    unsigned short* __restrict__ out_bf)    // bf16 [M,N]
{
  constexpr int NT = TN / 32;               // 4 (TN=128) or 2 (TN=64) n-tiles/wave
  const int nb = N / TN;
  int n0 = (blockIdx.x % nb) * TN;
  int m0 = (blockIdx.x / nb) << 7;
  int tid = threadIdx.x;
  int wave = tid >> 6, lane = tid & 63;
  int quad = lane >> 4, l16 = lane & 15;
  int wm = (wave & 1) << 6;                 // 0 / 64
  int wn = (wave >> 1) * (TN >> 1);         // 0 / TN/2

  __shared__ __align__(16) unsigned short As[128 * 32];
  __shared__ __align__(16) unsigned short Bs[TN * 32];

  f32x4 acc[4][NT];
#pragma unroll
  for (int i = 0; i < 4; ++i)
#pragma unroll
    for (int j = 0; j < NT; ++j) acc[i][j] = (f32x4){0.f, 0.f, 0.f, 0.f};

  int srow = lane >> 2;                     // 0..15
  int scol = (lane & 3) << 3;               // 0,8,16,24
  const unsigned short* gA0 = A + (size_t)(m0 + wave * 32 + srow) * K + scol;
  const unsigned short* gA1 = gA0 + (size_t)16 * K;
  unsigned short* lA0 = &As[(wave * 32) * 32];
  unsigned short* lA1 = &As[(wave * 32 + 16) * 32];
  const unsigned short* gB0;
  const unsigned short* gB1 = nullptr;
  unsigned short* lB0;
  unsigned short* lB1 = nullptr;
  if constexpr (TN == 128) {
    gB0 = Bt + (size_t)(n0 + wave * 32 + srow) * K + scol;
    gB1 = gB0 + (size_t)16 * K;
    lB0 = &Bs[(wave * 32) * 32];
    lB1 = &Bs[(wave * 32 + 16) * 32];
  } else {
    gB0 = Bt + (size_t)(n0 + wave * 16 + srow) * K + scol;
    lB0 = &Bs[(wave * 16) * 32];
  }

  for (int k0 = 0; k0 < K; k0 += 32) {
    gld16(gA0 + k0, lA0);
    gld16(gA1 + k0, lA1);
    gld16(gB0 + k0, lB0);
    if constexpr (TN == 128) gld16(gB1 + k0, lB1);
    __syncthreads();  // vmcnt(0) drain + barrier
    short8 af[4], bfr[NT];
#pragma unroll
    for (int t = 0; t < 4; ++t)
      af[t] = *(const short8*)(&As[(wm + t * 16 + l16) * 32 + quad * 8]);
#pragma unroll
    for (int t = 0; t < NT; ++t)
      bfr[t] = *(const short8*)(&Bs[(wn + t * 16 + l16) * 32 + quad * 8]);
#pragma unroll
    for (int i = 0; i < 4; ++i)
#pragma unroll
      for (int j = 0; j < NT; ++j)
        acc[i][j] = mfma16(af[i], bfr[j], acc[i][j]);
    __syncthreads();  // reads done before next stage overwrites
  }

#pragma unroll
  for (int mt = 0; mt < 4; ++mt)
#pragma unroll
    for (int nt = 0; nt < NT; ++nt) {
      f32x4 c = acc[mt][nt];
      int m = m0 + wm + mt * 16 + quad * 4;   // base row (r adds 0..3)
      int n = n0 + wn + nt * 16 + l16;
      if (MODE == MODE_QKV) {
        int bb = m >> 11, sIdx = m & 2047;
        if (n < 768) {
          float bs = bias0[n];
          int hh = n >> 6, d = n & 63;
          unsigned short* dst = out_q + (((size_t)(bb * NH + hh)) * SEQ + sIdx) * DH + d;
#pragma unroll
          for (int r = 0; r < 4; ++r) dst[r * DH] = f2bf(c[r] + bs);
        } else if (n < 1536) {
          int nn = n - 768;
          float bs = bias1[nn];
          int hh = nn >> 6, d = nn & 63;
          unsigned short* dst = out_k + (((size_t)(bb * NH + hh)) * SEQ + sIdx) * DH + d;
#pragma unroll
          for (int r = 0; r < 4; ++r) dst[r * DH] = f2bf(c[r] + bs);
        } else {
          int nn = n - 1536;
          float bs = bias2[nn];
          int hh = nn >> 6, d = nn & 63;
          uint2 pk;
          pk.x = pk2bf(c[0] + bs, c[1] + bs);
          pk.y = pk2bf(c[2] + bs, c[3] + bs);
          *(uint2*)(out_vT + (((size_t)(bb * NH + hh)) * DH + d) * SEQ + sIdx) = pk;
        }
      } else if (MODE == MODE_RESID) {
        float bs = bias0[n];
        const float* rp = resid + (size_t)m * N + n;
        float* op = out_f + (size_t)m * N + n;
#pragma unroll
        for (int r = 0; r < 4; ++r) op[(size_t)r * N] = rp[(size_t)r * N] + c[r] + bs;
      } else {  // MODE_GELU
        float bs = bias0[n];
        unsigned short* op = out_bf + (size_t)m * N + n;
#pragma unroll
        for (int r = 0; r < 4; ++r) {
          float t = c[r] + bs;
          op[(size_t)r * N] = f2bf(0.5f * t * (1.0f + erff(t * 0.70710678118654752f)));
        }
      }
    }
}

// ---------------- flash attention v3: key-split + combine ----------------
__global__ __launch_bounds__(256, 4) void flash_attn_kernel(
    const unsigned short* __restrict__ q,   // [B,NH,S,DH]
    const unsigned short* __restrict__ k,   // [B,NH,S,DH]
    const unsigned short* __restrict__ vT,  // [B,NH,DH,S]
    unsigned short* __restrict__ ctx)       // [MTOK,H] bf16
{
  const float CEXP = 0.18033688011112042f;  // 0.125 * log2(e)
  int bh = blockIdx.x >> 6;          // 24 (b,h)
  int qblk = blockIdx.x & 63;        // 64 q-blocks of 32
  int b = bh / NH, h = bh % NH;
  int tid = threadIdx.x;
  int wave = tid >> 6, lane = tid & 63;
  int quad = lane >> 4, l16 = lane & 15;
  int qbase = qblk << 5;

  const unsigned short* qp = q + ((size_t)bh * SEQ + qbase) * DH;
  const unsigned short* kp = k + (size_t)bh * SEQ * DH;
  const unsigned short* vp = vT + (size_t)bh * DH * SEQ;

  short8 qf00 = *(const short8*)(qp + l16 * DH + quad * 8);
  short8 qf01 = *(const short8*)(qp + l16 * DH + 32 + quad * 8);
  short8 qf10 = *(const short8*)(qp + (16 + l16) * DH + quad * 8);
  short8 qf11 = *(const short8*)(qp + (16 + l16) * DH + 32 + quad * 8);

  f32x4 oacc[2][4];
#pragma unroll
  for (int t = 0; t < 2; ++t)
#pragma unroll
    for (int dt = 0; dt < 4; ++dt) oacc[t][dt] = (f32x4){0.f, 0.f, 0.f, 0.f};
  float M[2] = {-3.0e38f, -3.0e38f};
  float L[2] = {0.f, 0.f};

  int addrA = ((((2 * quad) & 3) << 4) + l16) << 2;
  int addrB = ((((2 * quad + 1) & 3) << 4) + l16) << 2;
  bool loquad = quad < 2;

  int keylo = wave << 9;
  for (int key0 = keylo; key0 < keylo + 512; key0 += 32) {
    const unsigned short* k0p = kp + (size_t)(key0 + l16) * DH;
    const unsigned short* k1p = kp + (size_t)(key0 + 16 + l16) * DH;
    short8 ka0 = *(const short8*)(k0p + quad * 8);
    short8 ka1 = *(const short8*)(k0p + 32 + quad * 8);
    short8 kb0 = *(const short8*)(k1p + quad * 8);
    short8 kb1 = *(const short8*)(k1p + 32 + quad * 8);
    short8 vf0 = *(const short8*)(vp + (size_t)(0 * 16 + l16) * SEQ + key0 + quad * 8);
    short8 vf1 = *(const short8*)(vp + (size_t)(1 * 16 + l16) * SEQ + key0 + quad * 8);
    short8 vf2 = *(const short8*)(vp + (size_t)(2 * 16 + l16) * SEQ + key0 + quad * 8);
    short8 vf3 = *(const short8*)(vp + (size_t)(3 * 16 + l16) * SEQ + key0 + quad * 8);

#pragma unroll
    for (int t = 0; t < 2; ++t) {
      short8 q0 = t ? qf10 : qf00;
      short8 q1 = t ? qf11 : qf01;
      f32x4 s0 = (f32x4){0.f, 0.f, 0.f, 0.f};
      f32x4 s1 = (f32x4){0.f, 0.f, 0.f, 0.f};
      s0 = mfma16(ka0, q0, s0);
      s0 = mfma16(ka1, q1, s0);
      s1 = mfma16(kb0, q0, s1);
      s1 = mfma16(kb1, q1, s1);

      float cmax = fmaxf(fmaxf(fmaxf(s0[0], s0[1]), fmaxf(s0[2], s0[3])),
                         fmaxf(fmaxf(s1[0], s1[1]), fmaxf(s1[2], s1[3])));
      cmax = fmaxf(cmax, __shfl_xor(cmax, 16));
      cmax = fmaxf(cmax, __shfl_xor(cmax, 32));
      float m_new = fmaxf(M[t], cmax * CEXP);
      float alpha = __builtin_amdgcn_exp2f(M[t] - m_new);
      M[t] = m_new;

      f32x4 p0, p1;
#pragma unroll
      for (int r = 0; r < 4; ++r) {
        p0[r] = __builtin_amdgcn_exp2f(s0[r] * CEXP - m_new);
        p1[r] = __builtin_amdgcn_exp2f(s1[r] * CEXP - m_new);
      }
      float csum = (p0[0] + p0[1]) + (p0[2] + p0[3]) + (p1[0] + p1[1]) + (p1[2] + p1[3]);
      csum += __shfl_xor(csum, 16);
      csum += __shfl_xor(csum, 32);
      L[t] = L[t] * alpha + csum;

      int d00 = (int)pktrunc(p0[0], p0[1]);
      int d01 = (int)pktrunc(p0[2], p0[3]);
      int d10 = (int)pktrunc(p1[0], p1[1]);
      int d11 = (int)pktrunc(p1[2], p1[3]);

      int f0a = __builtin_amdgcn_ds_bpermute(addrA, d00);
      int f0b = __builtin_amdgcn_ds_bpermute(addrA, d10);
      int f1a = __builtin_amdgcn_ds_bpermute(addrA, d01);
      int f1b = __builtin_amdgcn_ds_bpermute(addrA, d11);
      int f2a = __builtin_amdgcn_ds_bpermute(addrB, d00);
      int f2b = __builtin_amdgcn_ds_bpermute(addrB, d10);
      int f3a = __builtin_amdgcn_ds_bpermute(addrB, d01);
      int f3b = __builtin_amdgcn_ds_bpermute(addrB, d11);
      union { short8 s; int i[4]; } pf;
      pf.i[0] = loquad ? f0a : f0b;
      pf.i[1] = loquad ? f1a : f1b;
      pf.i[2] = loquad ? f2a : f2b;
      pf.i[3] = loquad ? f3a : f3b;

#pragma unroll
      for (int dt = 0; dt < 4; ++dt)
#pragma unroll
        for (int r = 0; r < 4; ++r) oacc[t][dt][r] *= alpha;
      oacc[t][0] = mfma16(vf0, pf.s, oacc[t][0]);
      oacc[t][1] = mfma16(vf1, pf.s, oacc[t][1]);
      oacc[t][2] = mfma16(vf2, pf.s, oacc[t][2]);
      oacc[t][3] = mfma16(vf3, pf.s, oacc[t][3]);
    }
  }

  __shared__ float mbuf[4][2][16];
  __shared__ float lbuf[4][2][16];
  __shared__ uint2 obuf[4][2][4][64];

  if (lane < 16) {
    mbuf[wave][0][lane] = M[0];
    mbuf[wave][1][lane] = M[1];
  }
  __syncthreads();
#pragma unroll
  for (int t = 0; t < 2; ++t) {
    float m0 = mbuf[0][t][l16], m1 = mbuf[1][t][l16];
    float m2 = mbuf[2][t][l16], m3 = mbuf[3][t][l16];
    float mstar = fmaxf(fmaxf(m0, m1), fmaxf(m2, m3));
    float coef = __builtin_amdgcn_exp2f(M[t] - mstar);
    if (lane < 16) lbuf[wave][t][lane] = L[t] * coef;
#pragma unroll
    for (int dt = 0; dt < 4; ++dt) {
      uint2 pk;
      pk.x = pk2bf(oacc[t][dt][0] * coef, oacc[t][dt][1] * coef);
      pk.y = pk2bf(oacc[t][dt][2] * coef, oacc[t][dt][3] * coef);
      obuf[wave][t][dt][lane] = pk;
    }
  }
  __syncthreads();

#pragma unroll
  for (int pp = 0; pp < 2; ++pp) {
    int pi = wave * 2 + pp;
    int t = pi >> 2, dt = pi & 3;
    f32x4 sum = (f32x4){0.f, 0.f, 0.f, 0.f};
#pragma unroll
    for (int w = 0; w < 4; ++w) {
      uint2 pk = obuf[w][t][dt][lane];
      sum[0] += bf2f((unsigned short)(pk.x & 0xffff));
      sum[1] += bf2f((unsigned short)(pk.x >> 16));
      sum[2] += bf2f((unsigned short)(pk.y & 0xffff));
      sum[3] += bf2f((unsigned short)(pk.y >> 16));
    }
    float lstar = lbuf[0][t][l16] + lbuf[1][t][l16] + lbuf[2][t][l16] + lbuf[3][t][l16];
    float rinv = 1.0f / lstar;
    uint2 res;
    res.x = pk2bf(sum[0] * rinv, sum[1] * rinv);
    res.y = pk2bf(sum[2] * rinv, sum[3] * rinv);
    unsigned short* crow = ctx + (size_t)(b * SEQ + qbase + t * 16 + l16) * H
                           + h * DH + dt * 16 + quad * 4;
    *(uint2*)crow = res;
  }
}

// ---------------- launch ----------------
extern "C" void kernel_launch(void* const* d_in, const int* in_sizes, int n_in,
                              void* d_out, int out_size, void* d_ws, size_t ws_size,
                              hipStream_t stream) {
  const float* latent = (const float*)d_in[0];
  const float* ln1_w = (const float*)d_in[1];
  const float* ln1_b = (const float*)d_in[2];
  const float* Wq = (const float*)d_in[3];
  const float* bq = (const float*)d_in[4];
  const float* Wk = (const float*)d_in[5];
  const float* bk = (const float*)d_in[6];
  const float* Wv = (const float*)d_in[7];
  const float* bv = (const float*)d_in[8];
  const float* Wo = (const float*)d_in[9];
  const float* bo = (const float*)d_in[10];
  const float* ln2_w = (const float*)d_in[11];
  const float* ln2_b = (const float*)d_in[12];
  const float* W1 = (const float*)d_in[13];
  const float* b1 = (const float*)d_in[14];
  const float* W2 = (const float*)d_in[15];
  const float* b2 = (const float*)d_in[16];
  float* out = (float*)d_out;

  char* ws = (char*)d_ws;
  unsigned short* WqkvT = (unsigned short*)ws; ws += (size_t)2304 * 768 * 2;
  unsigned short* WoT   = (unsigned short*)ws; ws += (size_t)768 * 768 * 2;
  unsigned short* W1T   = (unsigned short*)ws; ws += (size_t)3072 * 768 * 2;
  unsigned short* W2T   = (unsigned short*)ws; ws += (size_t)768 * 3072 * 2;
  unsigned short* nx    = (unsigned short*)ws; ws += (size_t)MTOK * H * 2;
  unsigned short* nx2   = (unsigned short*)ws; ws += (size_t)MTOK * H * 2;
  unsigned short* qb    = (unsigned short*)ws; ws += (size_t)MTOK * H * 2;
  unsigned short* kb    = (unsigned short*)ws; ws += (size_t)MTOK * H * 2;
  unsigned short* vTb   = (unsigned short*)ws; ws += (size_t)MTOK * H * 2;
  unsigned short* ctx   = (unsigned short*)ws; ws += (size_t)MTOK * H * 2;
  unsigned short* hbuf  = (unsigned short*)ws; ws += (size_t)MTOK * FF * 2;
  float* x1             = (float*)ws;          ws += (size_t)MTOK * H * 4;

  // weights -> bf16, transposed; QKV packed into one [2304][768]
  transpose_cast<<<576, 256, 0, stream>>>(Wq, WqkvT, 768, 768);
  transpose_cast<<<576, 256, 0, stream>>>(Wk, WqkvT + (size_t)768 * 768, 768, 768);
  transpose_cast<<<576, 256, 0, stream>>>(Wv, WqkvT + (size_t)1536 * 768, 768, 768);
  transpose_cast<<<576, 256, 0, stream>>>(Wo, WoT, 768, 768);
  transpose_cast<<<2304, 256, 0, stream>>>(W1, W1T, 768, 3072);
  transpose_cast<<<2304, 256, 0, stream>>>(W2, W2T, 3072, 768);

  // LN1
  ln_kernel<<<MTOK, 256, 0, stream>>>(latent, ln1_w, ln1_b, nx);

  // QKV projection (fused, N=2304), 128x128 tiles
  gemm128<MODE_QKV, 128><<<32 * 18, 256, 0, stream>>>(
      nx, WqkvT, MTOK, 2304, 768, bq, bk, bv,
      nullptr, nullptr, qb, kb, vTb, nullptr);

  // attention (flash, key-split + combine)
  flash_attn_kernel<<<24 * 64, 256, 0, stream>>>(qb, kb, vTb, ctx);

  // output projection + residual -> x1 (fp32), 128x64 tiles
  gemm128<MODE_RESID, 64><<<32 * 12, 256, 0, stream>>>(
      ctx, WoT, MTOK, 768, 768, bo, nullptr, nullptr,
      latent, x1, nullptr, nullptr, nullptr, nullptr);

  // LN2
  ln_kernel<<<MTOK, 256, 0, stream>>>(x1, ln2_w, ln2_b, nx2);

  // FFN up + GELU -> hbuf (bf16), 128x128 tiles
  gemm128<MODE_GELU, 128><<<32 * 24, 256, 0, stream>>>(
      nx2, W1T, MTOK, 3072, 768, b1, nullptr, nullptr,
      nullptr, nullptr, nullptr, nullptr, nullptr, hbuf);

  // FFN down + residual -> d_out (fp32), 128x64 tiles
  gemm128<MODE_RESID, 64><<<32 * 12, 256, 0, stream>>>(
      hbuf, W2T, MTOK, 768, 3072, b2, nullptr, nullptr,
      x1, out, nullptr, nullptr, nullptr, nullptr);
}